// Round 3
// baseline (2129.357 us; speedup 1.0000x reference)
//
#include <hip/hip_runtime.h>
#include <hip/hip_bf16.h>

#define N_NODES_C 100000
#define N_EDGES_C 500000
#define N_REL_C 6
#define IN_DIM_C 64
#define HID_C 128
#define HEADS_C 4
#define CPH_C 32
#define N_GRAPHS_C 1024
#define BKT_SH 7
#define BKT_SZ 128
#define NBKT 782          // ceil(100000/128)
#define BIN_CAP 1024      // mean 639, std 25 -> 15 sigma headroom

// ================= CSR build (bucket sort by dst) =================
__global__ __launch_bounds__(256) void bucket_scatter_kernel(const int* __restrict__ ei,
                                                             int* __restrict__ cursor,
                                                             int* __restrict__ bins) {
    int i = blockIdx.x * 256 + threadIdx.x;
    if (i >= N_REL_C * N_EDGES_C) return;
    int r = i / N_EDGES_C;
    int e = i - r * N_EDGES_C;
    int src = ei[(size_t)r * 2 * N_EDGES_C + e];
    int dst = ei[(size_t)r * 2 * N_EDGES_C + N_EDGES_C + e];
    int b = r * NBKT + (dst >> BKT_SH);
    int pos = atomicAdd(&cursor[b], 1);
    if (pos < BIN_CAP) bins[(size_t)b * BIN_CAP + pos] = ((dst & (BKT_SZ - 1)) << 17) | src;
}

// exclusive scan of bucket counts, per relation (one wave per relation)
__global__ void bucket_scan_kernel(const int* __restrict__ cursor, int* __restrict__ bbase) {
    int r = blockIdx.x;
    int lane = threadIdx.x;   // 64
    int carry = 0;
    for (int c0 = 0; c0 < NBKT; c0 += 64) {
        int idx = c0 + lane;
        int v = (idx < NBKT) ? cursor[r * NBKT + idx] : 0;
        int s = v;
#pragma unroll
        for (int off = 1; off < 64; off <<= 1) {
            int n = __shfl_up(s, off);
            if (lane >= off) s += n;
        }
        if (idx < NBKT) bbase[r * NBKT + idx] = s - v + carry;
        carry += __shfl(s, 63);
    }
}

// per-bucket counting sort -> srcids (dst-sorted) + rowptr
__global__ __launch_bounds__(256) void bucket_sort_kernel(const int* __restrict__ bins,
                                                          const int* __restrict__ cursor,
                                                          const int* __restrict__ bbase,
                                                          int* __restrict__ srcids,
                                                          int* __restrict__ rowptr) {
    __shared__ int cnt[BKT_SZ], pfx[BKT_SZ], cur[BKT_SZ];
    int bid = blockIdx.x;
    int r = bid / NBKT, b = bid - r * NBKT;
    int t = threadIdx.x;
    int n = cursor[r * NBKT + b];
    if (n > BIN_CAP) n = BIN_CAP;
    int base = bbase[r * NBKT + b];
    if (t < BKT_SZ) cnt[t] = 0;
    __syncthreads();
    const int* bp = bins + (size_t)(r * NBKT + b) * BIN_CAP;
    for (int i = t; i < n; i += 256) atomicAdd(&cnt[bp[i] >> 17], 1);
    __syncthreads();
    if (t < 64) {
        int v0 = cnt[t];
        int s = v0;
#pragma unroll
        for (int off = 1; off < 64; off <<= 1) { int x = __shfl_up(s, off); if (t >= off) s += x; }
        pfx[t] = s - v0;
        int tot = __shfl(s, 63);
        int v1 = cnt[64 + t];
        int s1 = v1;
#pragma unroll
        for (int off = 1; off < 64; off <<= 1) { int x = __shfl_up(s1, off); if (t >= off) s1 += x; }
        pfx[64 + t] = s1 - v1 + tot;
    }
    __syncthreads();
    if (t < BKT_SZ) {
        cur[t] = 0;
        int node = b * BKT_SZ + t;
        if (node < N_NODES_C) rowptr[(size_t)r * (N_NODES_C + 1) + node] = base + pfx[t];
    }
    if (bid == 0 && t == 0) {
#pragma unroll
        for (int rr = 0; rr < N_REL_C; rr++)
            rowptr[(size_t)rr * (N_NODES_C + 1) + N_NODES_C] = N_EDGES_C;
    }
    __syncthreads();
    for (int i = t; i < n; i += 256) {
        int v = bp[i];
        int d = v >> 17;
        int pos = base + pfx[d] + atomicAdd(&cur[d], 1);
        srcids[(size_t)r * N_EDGES_C + pos] = v & 131071;
    }
}

// ================= GEMM (64x128 tile, 8x4/thread) + attn-logit epilogue ====
template <int K>
__global__ __launch_bounds__(256) void gemm_nodes(const float* __restrict__ X,
                                                  const float* __restrict__ Wbase,
                                                  const float* __restrict__ bias,
                                                  float* __restrict__ Hbase, int nrows,
                                                  const float* __restrict__ asbase,
                                                  const float* __restrict__ adbase,
                                                  float* __restrict__ alsbase,
                                                  float* __restrict__ aldbase) {
    __shared__ float Wl[64 * HID_C];   // 32 KB
    __shared__ float Xl[64 * K];       // 16/32 KB
    const int t = threadIdx.x;
    const int n0 = blockIdx.x * 64;
    const int slot = blockIdx.y;
    const float* W = Wbase + (size_t)slot * K * HID_C;
    float* H = Hbase + (size_t)slot * N_NODES_C * HID_C;

    for (int i = t; i < 64 * K / 4; i += 256) {
        int row = i / (K / 4);
        int col4 = i - row * (K / 4);
        float4 v = make_float4(0.f, 0.f, 0.f, 0.f);
        if (n0 + row < nrows) v = ((const float4*)(X + (size_t)(n0 + row) * K))[col4];
        ((float4*)Xl)[i] = v;
    }

    const int cg = t & 31, rg = t >> 5;
    const int c0 = cg * 4, r0 = rg * 8;
    float acc[8][4];
#pragma unroll
    for (int i = 0; i < 8; i++)
#pragma unroll
        for (int j = 0; j < 4; j++) acc[i][j] = 0.f;

    for (int kb = 0; kb < K; kb += 64) {
        __syncthreads();
        for (int i = t; i < 64 * HID_C / 4; i += 256)
            ((float4*)Wl)[i] = ((const float4*)(W + (size_t)kb * HID_C))[i];
        __syncthreads();
        for (int k = 0; k < 64; k += 4) {
            float4 wv[4];
#pragma unroll
            for (int kk = 0; kk < 4; kk++)
                wv[kk] = *(const float4*)&Wl[(k + kk) * HID_C + c0];
#pragma unroll
            for (int i = 0; i < 8; i++) {
                float4 xv = *(const float4*)&Xl[(r0 + i) * K + kb + k];
                acc[i][0] = fmaf(xv.x, wv[0].x, acc[i][0]);
                acc[i][1] = fmaf(xv.x, wv[0].y, acc[i][1]);
                acc[i][2] = fmaf(xv.x, wv[0].z, acc[i][2]);
                acc[i][3] = fmaf(xv.x, wv[0].w, acc[i][3]);
                acc[i][0] = fmaf(xv.y, wv[1].x, acc[i][0]);
                acc[i][1] = fmaf(xv.y, wv[1].y, acc[i][1]);
                acc[i][2] = fmaf(xv.y, wv[1].z, acc[i][2]);
                acc[i][3] = fmaf(xv.y, wv[1].w, acc[i][3]);
                acc[i][0] = fmaf(xv.z, wv[2].x, acc[i][0]);
                acc[i][1] = fmaf(xv.z, wv[2].y, acc[i][1]);
                acc[i][2] = fmaf(xv.z, wv[2].z, acc[i][2]);
                acc[i][3] = fmaf(xv.z, wv[2].w, acc[i][3]);
                acc[i][0] = fmaf(xv.w, wv[3].x, acc[i][0]);
                acc[i][1] = fmaf(xv.w, wv[3].y, acc[i][1]);
                acc[i][2] = fmaf(xv.w, wv[3].z, acc[i][2]);
                acc[i][3] = fmaf(xv.w, wv[3].w, acc[i][3]);
            }
        }
    }

    float4 bv = make_float4(0.f, 0.f, 0.f, 0.f);
    if (bias) bv = ((const float4*)bias)[cg];
#pragma unroll
    for (int i = 0; i < 8; i++) {
        int row = n0 + r0 + i;
        if (row < nrows) {
            float4 o;
            o.x = acc[i][0] + bv.x; o.y = acc[i][1] + bv.y;
            o.z = acc[i][2] + bv.z; o.w = acc[i][3] + bv.w;
            *(float4*)&H[(size_t)row * HID_C + c0] = o;
        }
    }

    if (alsbase) {
        const float* a_s = asbase + slot * HID_C;
        const float* a_d = adbase + slot * HID_C;
        float* als = alsbase + (size_t)slot * N_NODES_C * HEADS_C;
        float* ald = aldbase + (size_t)slot * N_NODES_C * HEADS_C;
        const int head = cg >> 3;
        const int coff = c0 & 31;
        float as4[4], ad4[4];
#pragma unroll
        for (int j = 0; j < 4; j++) {
            as4[j] = a_s[head * CPH_C + coff + j];
            ad4[j] = a_d[head * CPH_C + coff + j];
        }
        float ps[8], pd[8];
#pragma unroll
        for (int i = 0; i < 8; i++) {
            float s = 0.f, d = 0.f;
#pragma unroll
            for (int j = 0; j < 4; j++) {
                s = fmaf(acc[i][j], as4[j], s);
                d = fmaf(acc[i][j], ad4[j], d);
            }
            ps[i] = s; pd[i] = d;
        }
#pragma unroll
        for (int off = 1; off < 8; off <<= 1) {
#pragma unroll
            for (int i = 0; i < 8; i++) {
                ps[i] += __shfl_xor(ps[i], off);
                pd[i] += __shfl_xor(pd[i], off);
            }
        }
        if ((t & 7) == 0) {
#pragma unroll
            for (int i = 0; i < 8; i++) {
                int row = n0 + r0 + i;
                if (row < nrows) {
                    als[row * HEADS_C + head] = ps[i];
                    ald[row * HEADS_C + head] = pd[i];
                }
            }
        }
    }
}

// ========== fused multi-relation aggregate + bias + softsign + LN ==========
// one wave per dst node; lane handles channels 2l,2l+1; head = lane>>4
__global__ __launch_bounds__(256) void csr_agg_kernel(
    const int* __restrict__ rowptr, const int* __restrict__ srcids,
    const float* __restrict__ A, const float* __restrict__ als,
    const float* __restrict__ ald, int rel_start, int rel_cnt,
    const float* __restrict__ bias,   // non-null => first group (init from bias)
    float* __restrict__ B,            // partial accumulator buffer
    int last,                         // 1 => apply softsign+LN, write Cb
    const float* __restrict__ g, const float* __restrict__ be,
    float* __restrict__ Cb) {
    int node = blockIdx.x * 4 + (threadIdx.x >> 6);
    int lane = threadIdx.x & 63;
    int h0 = lane >> 4;
    int c = lane * 2;
    float a0, a1;
    if (bias) {
        a0 = 0.f; a1 = 0.f;
#pragma unroll
        for (int r = 0; r < N_REL_C; r++) {
            a0 += bias[r * HID_C + c];
            a1 += bias[r * HID_C + c + 1];
        }
    } else {
        float2 bv = *(const float2*)(B + (size_t)node * HID_C + c);
        a0 = bv.x; a1 = bv.y;
    }
    for (int j = 0; j < rel_cnt; j++) {
        int r = rel_start + j;
        const int* rp = rowptr + (size_t)r * (N_NODES_C + 1);
        const int* sp = srcids + (size_t)r * N_EDGES_C;
        const float* Aj = A + (size_t)j * N_NODES_C * HID_C;
        const float* alj = als + (size_t)j * N_NODES_C * HEADS_C;
        float aldv = ald[(size_t)j * N_NODES_C * HEADS_C + node * HEADS_C + h0];
        int s = rp[node], e = rp[node + 1];
        float den = 0.f, s0 = 0.f, s1 = 0.f;
        float alv = 0.f;
        float2 hv = make_float2(0.f, 0.f);
        if (s < e) {
            int src = sp[s];
            alv = alj[src * HEADS_C + h0];
            hv = *(const float2*)(Aj + (size_t)src * HID_C + c);
        }
        for (int i = s; i < e; i++) {
            float nal = 0.f;
            float2 nhv = make_float2(0.f, 0.f);
            if (i + 1 < e) {
                int nsrc = sp[i + 1];
                nal = alj[nsrc * HEADS_C + h0];
                nhv = *(const float2*)(Aj + (size_t)nsrc * HID_C + c);
            }
            float v = alv + aldv;
            v = v > 0.f ? v : 0.2f * v;
            float ex = expf(v);
            den += ex;
            s0 = fmaf(ex, hv.x, s0);
            s1 = fmaf(ex, hv.y, s1);
            alv = nal; hv = nhv;
        }
        float inv = 1.f / (den + 1e-16f);
        a0 = fmaf(s0, inv, a0);
        a1 = fmaf(s1, inv, a1);
    }
    if (!last) {
        *(float2*)(B + (size_t)node * HID_C + c) = make_float2(a0, a1);
    } else {
        float t0 = a0 / (1.f + fabsf(a0));
        float t1 = a1 / (1.f + fabsf(a1));
        float sum = t0 + t1, sq = t0 * t0 + t1 * t1;
#pragma unroll
        for (int off = 1; off < 64; off <<= 1) {
            sum += __shfl_xor(sum, off);
            sq += __shfl_xor(sq, off);
        }
        float mu = sum * (1.f / 128.f);
        float var = sq * (1.f / 128.f) - mu * mu;
        float inv = rsqrtf(var + 1e-5f);
        float2 gv = *(const float2*)(g + c);
        float2 bev = *(const float2*)(be + c);
        float2 o;
        o.x = (t0 - mu) * inv * gv.x + bev.x;
        o.y = (t1 - mu) * inv * gv.y + bev.y;
        *(float2*)(Cb + (size_t)node * HID_C + c) = o;
    }
}

// ================= pooling =================
__device__ __forceinline__ int lower_bound_i(const int* __restrict__ a, int n, int v) {
    int lo = 0, hi = n;
    while (lo < hi) {
        int mid = (lo + hi) >> 1;
        if (a[mid] < v) lo = mid + 1; else hi = mid;
    }
    return lo;
}

__global__ void pool_kernel(const float* __restrict__ H, const int* __restrict__ batch,
                            const float* __restrict__ q, float* __restrict__ pooled) {
    int g = blockIdx.x;
    int lane = threadIdx.x;
    int start = lower_bound_i(batch, N_NODES_C, g);
    int end = lower_bound_i(batch, N_NODES_C, g + 1);
    float q0 = q[lane * 2], q1 = q[lane * 2 + 1];
    float p0 = 0.f, p1 = 0.f, den = 0.f;
    for (int n = start; n < end; n++) {
        float2 hv = *(const float2*)(H + (size_t)n * HID_C + lane * 2);
        float part = hv.x * q0 + hv.y * q1;
#pragma unroll
        for (int off = 1; off < 64; off <<= 1) part += __shfl_xor(part, off);
        float exs = expf(part);
        den += exs;
        p0 += exs * hv.x;
        p1 += exs * hv.y;
    }
    float w = 1.f / (den + 1e-16f);
    pooled[(size_t)g * HID_C + lane * 2] = p0 * w;
    pooled[(size_t)g * HID_C + lane * 2 + 1] = p1 * w;
}

extern "C" void kernel_launch(void* const* d_in, const int* in_sizes, int n_in,
                              void* d_out, int out_size, void* d_ws, size_t ws_size,
                              hipStream_t stream) {
    const float* x   = (const float*)d_in[0];
    const int* ei    = (const int*)d_in[1];
    const int* batch = (const int*)d_in[2];
    const float* W1  = (const float*)d_in[3];
    const float* as1 = (const float*)d_in[4];
    const float* ad1 = (const float*)d_in[5];
    const float* b1  = (const float*)d_in[6];
    const float* W2  = (const float*)d_in[7];
    const float* as2 = (const float*)d_in[8];
    const float* ad2 = (const float*)d_in[9];
    const float* b2  = (const float*)d_in[10];
    const float* g1  = (const float*)d_in[11];
    const float* be1 = (const float*)d_in[12];
    const float* g2  = (const float*)d_in[13];
    const float* be2 = (const float*)d_in[14];
    const float* q   = (const float*)d_in[15];
    const float* Wp  = (const float*)d_in[16];
    const float* bp  = (const float*)d_in[17];
    float* out = (float*)d_out;

    const size_t NH = (size_t)N_NODES_C * HID_C;     // 12.8M floats
    float* ws = (float*)d_ws;
    float* Cb = ws;
    float* B = Cb + NH;
    float* pooled = B + NH;                          // 131072
    int* rowptr = (int*)(pooled + (size_t)N_GRAPHS_C * HID_C);   // 600008
    int* srcids = rowptr + 600008;                   // 3,000,000
    int* cursor = srcids + 3000000;                  // 4696
    int* bbase  = cursor + 4696;                     // 4696

    // how many relation slots fit: fixed part + nA*(A slab + logits)
    const size_t fixed_bytes = ((2 * NH + (size_t)N_GRAPHS_C * HID_C) +
                                (600008 + 3000000 + 4696 + 4696)) * 4;
    const size_t slot_bytes = (NH + 2 * (size_t)N_NODES_C * HEADS_C) * 4;
    int nA = 1;
    if (ws_size > fixed_bytes) {
        size_t k = (ws_size - fixed_bytes) / slot_bytes;
        nA = (int)(k < 1 ? 1 : (k > 6 ? 6 : k));
    }
    float* als = (float*)(bbase + 4696);             // [nA][N][4]
    float* ald = als + (size_t)nA * N_NODES_C * HEADS_C;
    float* A   = ald + (size_t)nA * N_NODES_C * HEADS_C;   // [nA][N][128]
    int* bins  = (int*)A;   // aliased: only live during CSR build (19.2 MB <= 51.2 MB)

    // ---- CSR build ----
    hipMemsetAsync(cursor, 0, 4696 * sizeof(int), stream);
    const int ehg = (N_REL_C * N_EDGES_C + 255) / 256;
    bucket_scatter_kernel<<<ehg, 256, 0, stream>>>(ei, cursor, bins);
    bucket_scan_kernel<<<N_REL_C, 64, 0, stream>>>(cursor, bbase);
    bucket_sort_kernel<<<N_REL_C * NBKT, 256, 0, stream>>>(bins, cursor, bbase, srcids, rowptr);

    const int gemm_grid = (N_NODES_C + 63) / 64;     // 1563
    const int agg_grid = N_NODES_C / 4;              // 25000

    // ---- layer 1 ----
    for (int gs = 0; gs < N_REL_C; gs += nA) {
        int cnt = (N_REL_C - gs) < nA ? (N_REL_C - gs) : nA;
        gemm_nodes<IN_DIM_C><<<dim3(gemm_grid, cnt), 256, 0, stream>>>(
            x, W1 + (size_t)gs * IN_DIM_C * HID_C, nullptr, A, N_NODES_C,
            as1 + gs * HID_C, ad1 + gs * HID_C, als, ald);
        csr_agg_kernel<<<agg_grid, 256, 0, stream>>>(
            rowptr, srcids, A, als, ald, gs, cnt,
            (gs == 0) ? b1 : nullptr, B, (gs + cnt == N_REL_C) ? 1 : 0, g1, be1, Cb);
    }
    // ---- layer 2 ----
    for (int gs = 0; gs < N_REL_C; gs += nA) {
        int cnt = (N_REL_C - gs) < nA ? (N_REL_C - gs) : nA;
        gemm_nodes<HID_C><<<dim3(gemm_grid, cnt), 256, 0, stream>>>(
            Cb, W2 + (size_t)gs * HID_C * HID_C, nullptr, A, N_NODES_C,
            as2 + gs * HID_C, ad2 + gs * HID_C, als, ald);
        csr_agg_kernel<<<agg_grid, 256, 0, stream>>>(
            rowptr, srcids, A, als, ald, gs, cnt,
            (gs == 0) ? b2 : nullptr, B, (gs + cnt == N_REL_C) ? 1 : 0, g2, be2, Cb);
    }

    // ---- pooling + projection ----
    pool_kernel<<<N_GRAPHS_C, 64, 0, stream>>>(Cb, batch, q, pooled);
    gemm_nodes<HID_C><<<dim3(N_GRAPHS_C / 64, 1), 256, 0, stream>>>(
        pooled, Wp, bp, out, N_GRAPHS_C, nullptr, nullptr, nullptr, nullptr);
}

// Round 4
// 1583.841 us; speedup vs baseline: 1.3444x; 1.3444x over previous
//
#include <hip/hip_runtime.h>
#include <hip/hip_bf16.h>
#include <hip/hip_fp16.h>

#define N_NODES_C 100000
#define N_EDGES_C 500000
#define N_REL_C 6
#define IN_DIM_C 64
#define HID_C 128
#define HEADS_C 4
#define CPH_C 32
#define N_GRAPHS_C 1024
#define NBLK_SCAN 391   // ceil(100000/256)

typedef _Float16 f16x8 __attribute__((ext_vector_type(8)));
typedef float f32x4 __attribute__((ext_vector_type(4)));

// ================= CSR build (round-2 style: low-contention) =================
__global__ __launch_bounds__(256) void hist_kernel(const int* __restrict__ ei,
                                                   int* __restrict__ cnt) {
    int i = blockIdx.x * 256 + threadIdx.x;
    if (i >= N_REL_C * N_EDGES_C) return;
    int r = i / N_EDGES_C;
    int e = i - r * N_EDGES_C;
    int dst = ei[(size_t)r * 2 * N_EDGES_C + N_EDGES_C + e];
    atomicAdd(&cnt[r * N_NODES_C + dst], 1);
}

__global__ __launch_bounds__(256) void scan1_kernel(const int* __restrict__ cnt,
                                                    int* __restrict__ rowptr,
                                                    int* __restrict__ blocksums) {
    int r = blockIdx.y, b = blockIdx.x, t = threadIdx.x;
    int idx = b * 256 + t;
    int v = (idx < N_NODES_C) ? cnt[r * N_NODES_C + idx] : 0;
    int orig = v;
    int lane = t & 63, w = t >> 6;
#pragma unroll
    for (int off = 1; off < 64; off <<= 1) {
        int n = __shfl_up(v, off);
        if (lane >= off) v += n;
    }
    __shared__ int wt[4];
    if (lane == 63) wt[w] = v;
    __syncthreads();
    int add = 0;
    for (int i = 0; i < w; i++) add += wt[i];
    v += add;
    if (idx < N_NODES_C) rowptr[(size_t)r * (N_NODES_C + 1) + idx] = v - orig;
    if (t == 255) blocksums[r * NBLK_SCAN + b] = v;
}

__global__ __launch_bounds__(512) void scan2_kernel(int* __restrict__ blocksums) {
    int r = blockIdx.x, t = threadIdx.x;
    int v = (t < NBLK_SCAN) ? blocksums[r * NBLK_SCAN + t] : 0;
    int orig = v;
    int lane = t & 63, w = t >> 6;
#pragma unroll
    for (int off = 1; off < 64; off <<= 1) {
        int n = __shfl_up(v, off);
        if (lane >= off) v += n;
    }
    __shared__ int wt[8];
    if (lane == 63) wt[w] = v;
    __syncthreads();
    int add = 0;
    for (int i = 0; i < w; i++) add += wt[i];
    v += add;
    if (t < NBLK_SCAN) blocksums[r * NBLK_SCAN + t] = v - orig;
}

__global__ __launch_bounds__(256) void scan3_kernel(int* __restrict__ rowptr,
                                                    const int* __restrict__ blocksums,
                                                    int* __restrict__ cursor) {
    int r = blockIdx.y, b = blockIdx.x, t = threadIdx.x;
    int idx = b * 256 + t;
    if (idx < N_NODES_C) {
        int val = rowptr[(size_t)r * (N_NODES_C + 1) + idx] + blocksums[r * NBLK_SCAN + b];
        rowptr[(size_t)r * (N_NODES_C + 1) + idx] = val;
        cursor[r * N_NODES_C + idx] = val;
    }
    if (b == 0 && t == 0) rowptr[(size_t)r * (N_NODES_C + 1) + N_NODES_C] = N_EDGES_C;
}

__global__ __launch_bounds__(256) void scatter_kernel(const int* __restrict__ ei,
                                                      int* __restrict__ cursor,
                                                      int* __restrict__ srcids) {
    int i = blockIdx.x * 256 + threadIdx.x;
    if (i >= N_REL_C * N_EDGES_C) return;
    int r = i / N_EDGES_C;
    int e = i - r * N_EDGES_C;
    int src = ei[(size_t)r * 2 * N_EDGES_C + e];
    int dst = ei[(size_t)r * 2 * N_EDGES_C + N_EDGES_C + e];
    int pos = atomicAdd(&cursor[r * N_NODES_C + dst], 1);
    srcids[(size_t)r * N_EDGES_C + pos] = src;
}

// ================= fp32 -> fp16 converts =================
__global__ __launch_bounds__(256) void convert_x_kernel(const float* __restrict__ x,
                                                        __half* __restrict__ xh, int n4) {
    int i = blockIdx.x * 256 + threadIdx.x;
    if (i >= n4) return;
    float4 v = ((const float4*)x)[i];
    union { __half h[4]; uint2 u; } u;
    u.h[0] = __float2half(v.x); u.h[1] = __float2half(v.y);
    u.h[2] = __float2half(v.z); u.h[3] = __float2half(v.w);
    ((uint2*)xh)[i] = u.u;
}

// Wt[r][n][k] = (half)W[r][k][n]
__global__ __launch_bounds__(256) void convert_w_kernel(const float* __restrict__ W1,
                                                        const float* __restrict__ W2,
                                                        __half* __restrict__ Wt1,
                                                        __half* __restrict__ Wt2) {
    int i = blockIdx.x * 256 + threadIdx.x;
    if (i < N_REL_C * IN_DIM_C * HID_C) {
        int r = i / (IN_DIM_C * HID_C);
        int rem = i - r * (IN_DIM_C * HID_C);
        int k = rem / HID_C, n = rem - k * HID_C;
        Wt1[(size_t)r * HID_C * IN_DIM_C + n * IN_DIM_C + k] = __float2half(W1[i]);
    }
    if (i < N_REL_C * HID_C * HID_C) {
        int r = i / (HID_C * HID_C);
        int rem = i - r * (HID_C * HID_C);
        int k = rem / HID_C, n = rem - k * HID_C;
        Wt2[(size_t)r * HID_C * HID_C + n * HID_C + k] = __float2half(W2[i]);
    }
}

// ================= fp16 MFMA GEMM + attn-logit epilogue =================
// H[100000x128] = Xh[100000xK] @ W[Kx128]; W given transposed Wt[n][k].
// block = 4 waves; wave computes 16 rows x 128 cols via 8 x mfma_16x16x32_f16.
// A/B fragments loaded directly from global (B table is L1-resident).
template <int K>
__global__ __launch_bounds__(256) void gemm_mfma_kernel(
    const __half* __restrict__ Xh, const __half* __restrict__ Wtbase,
    __half* __restrict__ Hbase,
    const float* __restrict__ asbase, const float* __restrict__ adbase,
    float* __restrict__ alsbase, float* __restrict__ aldbase) {
    const int slot = blockIdx.y;
    const __half* Wt = Wtbase + (size_t)slot * HID_C * K;
    __half* H = Hbase + (size_t)slot * N_NODES_C * HID_C;
    const int wave = threadIdx.x >> 6, lane = threadIdx.x & 63;
    const int r0 = blockIdx.x * 64 + wave * 16;
    const int m = lane & 15, quad = lane >> 4;
    int arow = r0 + m;
    if (arow > N_NODES_C - 1) arow = N_NODES_C - 1;   // clamp; OOB C rows unstored
    const __half* ap = Xh + (size_t)arow * K + quad * 8;
    const __half* bp = Wt + (size_t)m * K + quad * 8;

    f32x4 acc[8];
#pragma unroll
    for (int t = 0; t < 8; t++) acc[t] = (f32x4){0.f, 0.f, 0.f, 0.f};

#pragma unroll
    for (int kc = 0; kc < K; kc += 32) {
        f16x8 a = *(const f16x8*)(ap + kc);
#pragma unroll
        for (int t = 0; t < 8; t++) {
            f16x8 b = *(const f16x8*)(bp + (size_t)t * 16 * K + kc);
            acc[t] = __builtin_amdgcn_mfma_f32_16x16x32_f16(a, b, acc[t], 0, 0, 0);
        }
    }

    // store H fp16: C/D layout col=lane&15, row=quad*4+i
#pragma unroll
    for (int i = 0; i < 4; i++) {
        int R = r0 + quad * 4 + i;
        if (R < N_NODES_C) {
            __half* hp = H + (size_t)R * HID_C + m;
#pragma unroll
            for (int t = 0; t < 8; t++) hp[t * 16] = __float2half(acc[t][i]);
        }
    }

    // attention logits from fp32 accumulators
    const float* a_s = asbase + slot * HID_C;
    const float* a_d = adbase + slot * HID_C;
    float* als = alsbase + (size_t)slot * N_NODES_C * HEADS_C;
    float* ald = aldbase + (size_t)slot * N_NODES_C * HEADS_C;
    float ps[4][4], pd[4][4];
#pragma unroll
    for (int h = 0; h < 4; h++) {
        float as0 = a_s[h * 32 + m], as1 = a_s[h * 32 + 16 + m];
        float ad0 = a_d[h * 32 + m], ad1 = a_d[h * 32 + 16 + m];
#pragma unroll
        for (int i = 0; i < 4; i++) {
            ps[h][i] = acc[2 * h][i] * as0 + acc[2 * h + 1][i] * as1;
            pd[h][i] = acc[2 * h][i] * ad0 + acc[2 * h + 1][i] * ad1;
        }
    }
#pragma unroll
    for (int off = 1; off < 16; off <<= 1) {
#pragma unroll
        for (int h = 0; h < 4; h++)
#pragma unroll
            for (int i = 0; i < 4; i++) {
                ps[h][i] += __shfl_xor(ps[h][i], off);
                pd[h][i] += __shfl_xor(pd[h][i], off);
            }
    }
#pragma unroll
    for (int h = 0; h < 4; h++) {
        if (m == h) {
#pragma unroll
            for (int i = 0; i < 4; i++) {
                int R = r0 + quad * 4 + i;
                if (R < N_NODES_C) {
                    als[R * HEADS_C + h] = ps[h][i];
                    ald[R * HEADS_C + h] = pd[h][i];
                }
            }
        }
    }
}

// ========== fused multi-relation aggregate + bias + softsign + LN ==========
// one wave per dst node; lane handles channels 2l,2l+1; head = lane>>4
__global__ __launch_bounds__(256) void csr_agg_kernel(
    const int* __restrict__ rowptr, const int* __restrict__ srcids,
    const __half* __restrict__ A, const float* __restrict__ als,
    const float* __restrict__ ald, int rel_start, int rel_cnt,
    const float* __restrict__ bias,   // non-null => first group (init from bias)
    float* __restrict__ B,            // partial accumulator buffer
    int last,                         // 1 => apply softsign+LN
    const float* __restrict__ g, const float* __restrict__ be,
    float* __restrict__ Cb, __half* __restrict__ Cbh) {
    int node = blockIdx.x * 4 + (threadIdx.x >> 6);
    int lane = threadIdx.x & 63;
    int h0 = lane >> 4;
    int c = lane * 2;
    float a0, a1;
    if (bias) {
        a0 = 0.f; a1 = 0.f;
#pragma unroll
        for (int r = 0; r < N_REL_C; r++) {
            a0 += bias[r * HID_C + c];
            a1 += bias[r * HID_C + c + 1];
        }
    } else {
        float2 bv = *(const float2*)(B + (size_t)node * HID_C + c);
        a0 = bv.x; a1 = bv.y;
    }
    for (int j = 0; j < rel_cnt; j++) {
        int r = rel_start + j;
        const int* rp = rowptr + (size_t)r * (N_NODES_C + 1);
        const int* sp = srcids + (size_t)r * N_EDGES_C;
        const __half* Aj = A + (size_t)j * N_NODES_C * HID_C;
        const float* alj = als + (size_t)j * N_NODES_C * HEADS_C;
        float aldv = ald[(size_t)j * N_NODES_C * HEADS_C + node * HEADS_C + h0];
        int s = rp[node], e = rp[node + 1];
        float den = 0.f, s0 = 0.f, s1 = 0.f;
        float alv = 0.f;
        float2 hv = make_float2(0.f, 0.f);
        if (s < e) {
            int src = sp[s];
            alv = alj[src * HEADS_C + h0];
            hv = __half22float2(*(const __half2*)(Aj + (size_t)src * HID_C + c));
        }
        for (int i = s; i < e; i++) {
            float nal = 0.f;
            float2 nhv = make_float2(0.f, 0.f);
            if (i + 1 < e) {
                int nsrc = sp[i + 1];
                nal = alj[nsrc * HEADS_C + h0];
                nhv = __half22float2(*(const __half2*)(Aj + (size_t)nsrc * HID_C + c));
            }
            float v = alv + aldv;
            v = v > 0.f ? v : 0.2f * v;
            float ex = expf(v);
            den += ex;
            s0 = fmaf(ex, hv.x, s0);
            s1 = fmaf(ex, hv.y, s1);
            alv = nal; hv = nhv;
        }
        float inv = 1.f / (den + 1e-16f);
        a0 = fmaf(s0, inv, a0);
        a1 = fmaf(s1, inv, a1);
    }
    if (!last) {
        *(float2*)(B + (size_t)node * HID_C + c) = make_float2(a0, a1);
    } else {
        float t0 = a0 / (1.f + fabsf(a0));
        float t1 = a1 / (1.f + fabsf(a1));
        float sum = t0 + t1, sq = t0 * t0 + t1 * t1;
#pragma unroll
        for (int off = 1; off < 64; off <<= 1) {
            sum += __shfl_xor(sum, off);
            sq += __shfl_xor(sq, off);
        }
        float mu = sum * (1.f / 128.f);
        float var = sq * (1.f / 128.f) - mu * mu;
        float inv = rsqrtf(var + 1e-5f);
        float2 gv = *(const float2*)(g + c);
        float2 bev = *(const float2*)(be + c);
        float2 o;
        o.x = (t0 - mu) * inv * gv.x + bev.x;
        o.y = (t1 - mu) * inv * gv.y + bev.y;
        *(float2*)(Cb + (size_t)node * HID_C + c) = o;
        if (Cbh) *(__half2*)(Cbh + (size_t)node * HID_C + c) = __float22half2_rn(o);
    }
}

// ================= pooling + projection =================
__device__ __forceinline__ int lower_bound_i(const int* __restrict__ a, int n, int v) {
    int lo = 0, hi = n;
    while (lo < hi) {
        int mid = (lo + hi) >> 1;
        if (a[mid] < v) lo = mid + 1; else hi = mid;
    }
    return lo;
}

__global__ void pool_kernel(const float* __restrict__ H, const int* __restrict__ batch,
                            const float* __restrict__ q, float* __restrict__ pooled) {
    int g = blockIdx.x;
    int lane = threadIdx.x;
    int start = lower_bound_i(batch, N_NODES_C, g);
    int end = lower_bound_i(batch, N_NODES_C, g + 1);
    float q0 = q[lane * 2], q1 = q[lane * 2 + 1];
    float p0 = 0.f, p1 = 0.f, den = 0.f;
    for (int n = start; n < end; n++) {
        float2 hv = *(const float2*)(H + (size_t)n * HID_C + lane * 2);
        float part = hv.x * q0 + hv.y * q1;
#pragma unroll
        for (int off = 1; off < 64; off <<= 1) part += __shfl_xor(part, off);
        float exs = expf(part);
        den += exs;
        p0 += exs * hv.x;
        p1 += exs * hv.y;
    }
    float w = 1.f / (den + 1e-16f);
    pooled[(size_t)g * HID_C + lane * 2] = p0 * w;
    pooled[(size_t)g * HID_C + lane * 2 + 1] = p1 * w;
}

// out[g][c] = bp[c] + sum_k pooled[g][k] * Wp[k][c]; one block per graph
__global__ __launch_bounds__(128) void proj_kernel(const float* __restrict__ pooled,
                                                   const float* __restrict__ Wp,
                                                   const float* __restrict__ bp,
                                                   float* __restrict__ out) {
    int g = blockIdx.x, c = threadIdx.x;
    __shared__ float pl[HID_C];
    pl[c] = pooled[(size_t)g * HID_C + c];
    __syncthreads();
    float s = bp[c];
    for (int k = 0; k < HID_C; k++) s = fmaf(pl[k], Wp[k * HID_C + c], s);
    out[(size_t)g * HID_C + c] = s;
}

extern "C" void kernel_launch(void* const* d_in, const int* in_sizes, int n_in,
                              void* d_out, int out_size, void* d_ws, size_t ws_size,
                              hipStream_t stream) {
    const float* x   = (const float*)d_in[0];
    const int* ei    = (const int*)d_in[1];
    const int* batch = (const int*)d_in[2];
    const float* W1  = (const float*)d_in[3];
    const float* as1 = (const float*)d_in[4];
    const float* ad1 = (const float*)d_in[5];
    const float* b1  = (const float*)d_in[6];
    const float* W2  = (const float*)d_in[7];
    const float* as2 = (const float*)d_in[8];
    const float* ad2 = (const float*)d_in[9];
    const float* b2  = (const float*)d_in[10];
    const float* g1  = (const float*)d_in[11];
    const float* be1 = (const float*)d_in[12];
    const float* g2  = (const float*)d_in[13];
    const float* be2 = (const float*)d_in[14];
    const float* q   = (const float*)d_in[15];
    const float* Wp  = (const float*)d_in[16];
    const float* bp  = (const float*)d_in[17];
    float* out = (float*)d_out;

    const size_t NH = (size_t)N_NODES_C * HID_C;     // 12.8M
    char* w = (char*)d_ws;
    float* Cb     = (float*)w;                        w += NH * 4;
    float* B      = (float*)w;                        w += NH * 4;
    float* pooled = (float*)w;                        w += (size_t)N_GRAPHS_C * HID_C * 4;
    __half* xh    = (__half*)w;                       w += (size_t)N_NODES_C * IN_DIM_C * 2;
    __half* Cbh   = (__half*)w;                       w += NH * 2;
    __half* Wt1   = (__half*)w;                       w += (size_t)N_REL_C * IN_DIM_C * HID_C * 2;
    __half* Wt2   = (__half*)w;                       w += (size_t)N_REL_C * HID_C * HID_C * 2;
    int* rowptr   = (int*)w;                          w += (size_t)N_REL_C * (N_NODES_C + 1) * 4;
    int* srcids   = (int*)w;                          w += (size_t)N_REL_C * N_EDGES_C * 4;
    int* cnt      = (int*)w;                          w += (size_t)N_REL_C * N_NODES_C * 4;
    int* cursor   = (int*)w;                          w += (size_t)N_REL_C * N_NODES_C * 4;
    int* bsums    = (int*)w;                          w += (size_t)N_REL_C * NBLK_SCAN * 4;

    // adaptive relation-group width: slot = A (fp16 H) + als + ald
    const size_t fixed_bytes = (size_t)(w - (char*)d_ws);
    const size_t slot_bytes = NH * 2 + 2 * (size_t)N_NODES_C * HEADS_C * 4;
    int nA = 1;
    if (ws_size > fixed_bytes) {
        size_t k = (ws_size - fixed_bytes) / slot_bytes;
        nA = (int)(k < 1 ? 1 : (k > 6 ? 6 : k));
    }
    float* als = (float*)w;
    float* ald = als + (size_t)nA * N_NODES_C * HEADS_C;
    __half* A  = (__half*)(ald + (size_t)nA * N_NODES_C * HEADS_C);

    // ---- CSR build ----
    hipMemsetAsync(cnt, 0, (size_t)N_REL_C * N_NODES_C * sizeof(int), stream);
    const int ehg = (N_REL_C * N_EDGES_C + 255) / 256;
    hist_kernel<<<ehg, 256, 0, stream>>>(ei, cnt);
    scan1_kernel<<<dim3(NBLK_SCAN, N_REL_C), 256, 0, stream>>>(cnt, rowptr, bsums);
    scan2_kernel<<<N_REL_C, 512, 0, stream>>>(bsums);
    scan3_kernel<<<dim3(NBLK_SCAN, N_REL_C), 256, 0, stream>>>(rowptr, bsums, cursor);
    scatter_kernel<<<ehg, 256, 0, stream>>>(ei, cursor, srcids);

    // ---- fp16 conversions ----
    convert_x_kernel<<<(N_NODES_C * IN_DIM_C / 4 + 255) / 256, 256, 0, stream>>>(
        x, xh, N_NODES_C * IN_DIM_C / 4);
    convert_w_kernel<<<(N_REL_C * HID_C * HID_C + 255) / 256, 256, 0, stream>>>(
        W1, W2, Wt1, Wt2);

    const int gemm_grid = (N_NODES_C + 63) / 64;     // 1563
    const int agg_grid = N_NODES_C / 4;              // 25000

    // ---- layer 1 ----
    for (int gs = 0; gs < N_REL_C; gs += nA) {
        int cnt2 = (N_REL_C - gs) < nA ? (N_REL_C - gs) : nA;
        gemm_mfma_kernel<IN_DIM_C><<<dim3(gemm_grid, cnt2), 256, 0, stream>>>(
            xh, Wt1 + (size_t)gs * IN_DIM_C * HID_C, A,
            as1 + gs * HID_C, ad1 + gs * HID_C, als, ald);
        csr_agg_kernel<<<agg_grid, 256, 0, stream>>>(
            rowptr, srcids, A, als, ald, gs, cnt2,
            (gs == 0) ? b1 : nullptr, B, (gs + cnt2 == N_REL_C) ? 1 : 0,
            g1, be1, Cb, Cbh);
    }
    // ---- layer 2 ----
    for (int gs = 0; gs < N_REL_C; gs += nA) {
        int cnt2 = (N_REL_C - gs) < nA ? (N_REL_C - gs) : nA;
        gemm_mfma_kernel<HID_C><<<dim3(gemm_grid, cnt2), 256, 0, stream>>>(
            Cbh, Wt2 + (size_t)gs * HID_C * HID_C, A,
            as2 + gs * HID_C, ad2 + gs * HID_C, als, ald);
        csr_agg_kernel<<<agg_grid, 256, 0, stream>>>(
            rowptr, srcids, A, als, ald, gs, cnt2,
            (gs == 0) ? b2 : nullptr, B, (gs + cnt2 == N_REL_C) ? 1 : 0,
            g2, be2, Cb, nullptr);
    }

    // ---- pooling + projection ----
    pool_kernel<<<N_GRAPHS_C, 64, 0, stream>>>(Cb, batch, q, pooled);
    proj_kernel<<<N_GRAPHS_C, 128, 0, stream>>>(pooled, Wp, bp, out);
}

// Round 5
// 1219.636 us; speedup vs baseline: 1.7459x; 1.2986x over previous
//
#include <hip/hip_runtime.h>
#include <hip/hip_bf16.h>
#include <hip/hip_fp16.h>

#define N_NODES_C 100000
#define N_EDGES_C 500000
#define N_REL_C 6
#define IN_DIM_C 64
#define HID_C 128
#define HEADS_C 4
#define CPH_C 32
#define N_GRAPHS_C 1024
#define NBLK_SCAN 391   // ceil(100000/256)

typedef _Float16 f16x8 __attribute__((ext_vector_type(8)));
typedef float f32x4 __attribute__((ext_vector_type(4)));

// ================= CSR build =================
__global__ __launch_bounds__(256) void hist_kernel(const int* __restrict__ ei,
                                                   int* __restrict__ cnt) {
    int i = blockIdx.x * 256 + threadIdx.x;
    if (i >= N_REL_C * N_EDGES_C) return;
    int r = i / N_EDGES_C;
    int e = i - r * N_EDGES_C;
    int dst = ei[(size_t)r * 2 * N_EDGES_C + N_EDGES_C + e];
    atomicAdd(&cnt[r * N_NODES_C + dst], 1);
}

__global__ __launch_bounds__(256) void scan1_kernel(const int* __restrict__ cnt,
                                                    int* __restrict__ rowptr,
                                                    int* __restrict__ blocksums) {
    int r = blockIdx.y, b = blockIdx.x, t = threadIdx.x;
    int idx = b * 256 + t;
    int v = (idx < N_NODES_C) ? cnt[r * N_NODES_C + idx] : 0;
    int orig = v;
    int lane = t & 63, w = t >> 6;
#pragma unroll
    for (int off = 1; off < 64; off <<= 1) {
        int n = __shfl_up(v, off);
        if (lane >= off) v += n;
    }
    __shared__ int wt[4];
    if (lane == 63) wt[w] = v;
    __syncthreads();
    int add = 0;
    for (int i = 0; i < w; i++) add += wt[i];
    v += add;
    if (idx < N_NODES_C) rowptr[(size_t)r * (N_NODES_C + 1) + idx] = v - orig;
    if (t == 255) blocksums[r * NBLK_SCAN + b] = v;
}

__global__ __launch_bounds__(512) void scan2_kernel(int* __restrict__ blocksums) {
    int r = blockIdx.x, t = threadIdx.x;
    int v = (t < NBLK_SCAN) ? blocksums[r * NBLK_SCAN + t] : 0;
    int orig = v;
    int lane = t & 63, w = t >> 6;
#pragma unroll
    for (int off = 1; off < 64; off <<= 1) {
        int n = __shfl_up(v, off);
        if (lane >= off) v += n;
    }
    __shared__ int wt[8];
    if (lane == 63) wt[w] = v;
    __syncthreads();
    int add = 0;
    for (int i = 0; i < w; i++) add += wt[i];
    v += add;
    if (t < NBLK_SCAN) blocksums[r * NBLK_SCAN + t] = v - orig;
}

__global__ __launch_bounds__(256) void scan3_kernel(int* __restrict__ rowptr,
                                                    const int* __restrict__ blocksums,
                                                    int* __restrict__ cursor) {
    int r = blockIdx.y, b = blockIdx.x, t = threadIdx.x;
    int idx = b * 256 + t;
    if (idx < N_NODES_C) {
        int val = rowptr[(size_t)r * (N_NODES_C + 1) + idx] + blocksums[r * NBLK_SCAN + b];
        rowptr[(size_t)r * (N_NODES_C + 1) + idx] = val;
        cursor[r * N_NODES_C + idx] = val;
    }
    if (b == 0 && t == 0) rowptr[(size_t)r * (N_NODES_C + 1) + N_NODES_C] = N_EDGES_C;
}

__global__ __launch_bounds__(256) void scatter_kernel(const int* __restrict__ ei,
                                                      int* __restrict__ cursor,
                                                      int* __restrict__ srcids) {
    int i = blockIdx.x * 256 + threadIdx.x;
    if (i >= N_REL_C * N_EDGES_C) return;
    int r = i / N_EDGES_C;
    int e = i - r * N_EDGES_C;
    int src = ei[(size_t)r * 2 * N_EDGES_C + e];
    int dst = ei[(size_t)r * 2 * N_EDGES_C + N_EDGES_C + e];
    int pos = atomicAdd(&cursor[r * N_NODES_C + dst], 1);
    srcids[(size_t)r * N_EDGES_C + pos] = src;
}

// ================= fp32 -> fp16 converts =================
__global__ __launch_bounds__(256) void convert_x_kernel(const float* __restrict__ x,
                                                        __half* __restrict__ xh, int n4) {
    int i = blockIdx.x * 256 + threadIdx.x;
    if (i >= n4) return;
    float4 v = ((const float4*)x)[i];
    union { __half h[4]; uint2 u; } u;
    u.h[0] = __float2half(v.x); u.h[1] = __float2half(v.y);
    u.h[2] = __float2half(v.z); u.h[3] = __float2half(v.w);
    ((uint2*)xh)[i] = u.u;
}

__global__ __launch_bounds__(256) void convert_w_kernel(const float* __restrict__ W1,
                                                        const float* __restrict__ W2,
                                                        __half* __restrict__ Wt1,
                                                        __half* __restrict__ Wt2) {
    int i = blockIdx.x * 256 + threadIdx.x;
    if (i < N_REL_C * IN_DIM_C * HID_C) {
        int r = i / (IN_DIM_C * HID_C);
        int rem = i - r * (IN_DIM_C * HID_C);
        int k = rem / HID_C, n = rem - k * HID_C;
        Wt1[(size_t)r * HID_C * IN_DIM_C + n * IN_DIM_C + k] = __float2half(W1[i]);
    }
    if (i < N_REL_C * HID_C * HID_C) {
        int r = i / (HID_C * HID_C);
        int rem = i - r * (HID_C * HID_C);
        int k = rem / HID_C, n = rem - k * HID_C;
        Wt2[(size_t)r * HID_C * HID_C + n * HID_C + k] = __float2half(W2[i]);
    }
}

// ================= fp16 MFMA GEMM + attn-logit epilogue =================
template <int K>
__global__ __launch_bounds__(256) void gemm_mfma_kernel(
    const __half* __restrict__ Xh, const __half* __restrict__ Wtbase,
    __half* __restrict__ Hbase,
    const float* __restrict__ asbase, const float* __restrict__ adbase,
    float* __restrict__ alsbase, float* __restrict__ aldbase) {
    const int slot = blockIdx.y;
    const __half* Wt = Wtbase + (size_t)slot * HID_C * K;
    __half* H = Hbase + (size_t)slot * N_NODES_C * HID_C;
    const int wave = threadIdx.x >> 6, lane = threadIdx.x & 63;
    const int r0 = blockIdx.x * 64 + wave * 16;
    const int m = lane & 15, quad = lane >> 4;
    int arow = r0 + m;
    if (arow > N_NODES_C - 1) arow = N_NODES_C - 1;
    const __half* ap = Xh + (size_t)arow * K + quad * 8;
    const __half* bp = Wt + (size_t)m * K + quad * 8;

    f32x4 acc[8];
#pragma unroll
    for (int t = 0; t < 8; t++) acc[t] = (f32x4){0.f, 0.f, 0.f, 0.f};

#pragma unroll
    for (int kc = 0; kc < K; kc += 32) {
        f16x8 a = *(const f16x8*)(ap + kc);
#pragma unroll
        for (int t = 0; t < 8; t++) {
            f16x8 b = *(const f16x8*)(bp + (size_t)t * 16 * K + kc);
            acc[t] = __builtin_amdgcn_mfma_f32_16x16x32_f16(a, b, acc[t], 0, 0, 0);
        }
    }

#pragma unroll
    for (int i = 0; i < 4; i++) {
        int R = r0 + quad * 4 + i;
        if (R < N_NODES_C) {
            __half* hp = H + (size_t)R * HID_C + m;
#pragma unroll
            for (int t = 0; t < 8; t++) hp[t * 16] = __float2half(acc[t][i]);
        }
    }

    const float* a_s = asbase + slot * HID_C;
    const float* a_d = adbase + slot * HID_C;
    float* als = alsbase + (size_t)slot * N_NODES_C * HEADS_C;
    float* ald = aldbase + (size_t)slot * N_NODES_C * HEADS_C;
    float ps[4][4], pd[4][4];
#pragma unroll
    for (int h = 0; h < 4; h++) {
        float as0 = a_s[h * 32 + m], as1 = a_s[h * 32 + 16 + m];
        float ad0 = a_d[h * 32 + m], ad1 = a_d[h * 32 + 16 + m];
#pragma unroll
        for (int i = 0; i < 4; i++) {
            ps[h][i] = acc[2 * h][i] * as0 + acc[2 * h + 1][i] * as1;
            pd[h][i] = acc[2 * h][i] * ad0 + acc[2 * h + 1][i] * ad1;
        }
    }
#pragma unroll
    for (int off = 1; off < 16; off <<= 1) {
#pragma unroll
        for (int h = 0; h < 4; h++)
#pragma unroll
            for (int i = 0; i < 4; i++) {
                ps[h][i] += __shfl_xor(ps[h][i], off);
                pd[h][i] += __shfl_xor(pd[h][i], off);
            }
    }
#pragma unroll
    for (int h = 0; h < 4; h++) {
        if (m == h) {
#pragma unroll
            for (int i = 0; i < 4; i++) {
                int R = r0 + quad * 4 + i;
                if (R < N_NODES_C) {
                    als[R * HEADS_C + h] = ps[h][i];
                    ald[R * HEADS_C + h] = pd[h][i];
                }
            }
        }
    }
}

// ========== fused multi-relation aggregate + bias + softsign + LN ==========
// one wave per dst node; 4 edge-groups of 16 lanes; lane j16 covers
// channels 8*j16..8*j16+7 (head = j16>>2). Groups stride the edge list by 4.
__global__ __launch_bounds__(256) void csr_agg_kernel(
    const int* __restrict__ rowptr, const int* __restrict__ srcids,
    const __half* __restrict__ A, const float* __restrict__ als,
    const float* __restrict__ ald, int rel_start, int rel_cnt,
    const float* __restrict__ bias, int first, int last,
    float* __restrict__ B,           // partial accumulator (nA<6 only)
    const float* __restrict__ g, const float* __restrict__ be,
    __half* __restrict__ Cbh) {
    int node = blockIdx.x * 4 + (threadIdx.x >> 6);
    int lane = threadIdx.x & 63;
    int grp = lane >> 4;      // edge group 0..3
    int j16 = lane & 15;      // channel lane: ch 8*j16 ..
    int head = j16 >> 2;
    int cbase = j16 * 8;

    float acc[8];
    if (first) {
#pragma unroll
        for (int t = 0; t < 8; t++) {
            float s = 0.f;
#pragma unroll
            for (int r = 0; r < N_REL_C; r++) s += bias[r * HID_C + cbase + t];
            acc[t] = s;
        }
    } else {
        float4 b0 = *(const float4*)(B + (size_t)node * HID_C + cbase);
        float4 b1 = *(const float4*)(B + (size_t)node * HID_C + cbase + 4);
        acc[0] = b0.x; acc[1] = b0.y; acc[2] = b0.z; acc[3] = b0.w;
        acc[4] = b1.x; acc[5] = b1.y; acc[6] = b1.z; acc[7] = b1.w;
    }

    for (int j = 0; j < rel_cnt; j++) {
        int r = rel_start + j;
        const int* rp = rowptr + (size_t)r * (N_NODES_C + 1);
        const int* sp = srcids + (size_t)r * N_EDGES_C;
        const __half* Aj = A + (size_t)j * N_NODES_C * HID_C;
        const float* alj = als + (size_t)j * N_NODES_C * HEADS_C;
        float aldv = ald[(size_t)j * N_NODES_C * HEADS_C + node * HEADS_C + head];
        int s = rp[node], e = rp[node + 1];
        float racc[8];
#pragma unroll
        for (int t = 0; t < 8; t++) racc[t] = 0.f;
        float rden = 0.f;
        int i = s + grp;
        int src = (i < e) ? sp[i] : 0;
        for (; i < e; i += 4) {
            int nsrc = (i + 4 < e) ? sp[i + 4] : 0;
            float v = alj[src * HEADS_C + head] + aldv;
            v = v > 0.f ? v : 0.2f * v;
            float ex = __expf(v);
            union { uint4 u; __half2 h2[4]; } rw;
            rw.u = *(const uint4*)(Aj + (size_t)src * HID_C + cbase);
            float2 f0 = __half22float2(rw.h2[0]);
            float2 f1 = __half22float2(rw.h2[1]);
            float2 f2 = __half22float2(rw.h2[2]);
            float2 f3 = __half22float2(rw.h2[3]);
            racc[0] = fmaf(ex, f0.x, racc[0]);
            racc[1] = fmaf(ex, f0.y, racc[1]);
            racc[2] = fmaf(ex, f1.x, racc[2]);
            racc[3] = fmaf(ex, f1.y, racc[3]);
            racc[4] = fmaf(ex, f2.x, racc[4]);
            racc[5] = fmaf(ex, f2.y, racc[5]);
            racc[6] = fmaf(ex, f3.x, racc[6]);
            racc[7] = fmaf(ex, f3.y, racc[7]);
            rden += ex;
            src = nsrc;
        }
        // cross-group reduce (groups partition the edge list)
#pragma unroll
        for (int off = 16; off < 64; off <<= 1) {
            rden += __shfl_xor(rden, off);
#pragma unroll
            for (int t = 0; t < 8; t++) racc[t] += __shfl_xor(racc[t], off);
        }
        float inv = 1.f / (rden + 1e-16f);
#pragma unroll
        for (int t = 0; t < 8; t++) acc[t] = fmaf(racc[t], inv, acc[t]);
    }

    if (!last) {
        if (grp == 0) {
            float4 o0 = make_float4(acc[0], acc[1], acc[2], acc[3]);
            float4 o1 = make_float4(acc[4], acc[5], acc[6], acc[7]);
            *(float4*)(B + (size_t)node * HID_C + cbase) = o0;
            *(float4*)(B + (size_t)node * HID_C + cbase + 4) = o1;
        }
    } else {
        float ss[8];
        float sum = 0.f, sq = 0.f;
#pragma unroll
        for (int t = 0; t < 8; t++) {
            float v = acc[t] / (1.f + fabsf(acc[t]));
            ss[t] = v;
            sum += v;
            sq = fmaf(v, v, sq);
        }
#pragma unroll
        for (int off = 1; off < 16; off <<= 1) {
            sum += __shfl_xor(sum, off);
            sq += __shfl_xor(sq, off);
        }
        float mu = sum * (1.f / 128.f);
        float var = sq * (1.f / 128.f) - mu * mu;
        float inv = rsqrtf(var + 1e-5f);
        if (grp == 0) {
            float4 gv0 = *(const float4*)(g + cbase);
            float4 gv1 = *(const float4*)(g + cbase + 4);
            float4 bv0 = *(const float4*)(be + cbase);
            float4 bv1 = *(const float4*)(be + cbase + 4);
            union { uint4 u; __half2 h2[4]; } ow;
            ow.h2[0] = __float22half2_rn(make_float2(
                (ss[0] - mu) * inv * gv0.x + bv0.x, (ss[1] - mu) * inv * gv0.y + bv0.y));
            ow.h2[1] = __float22half2_rn(make_float2(
                (ss[2] - mu) * inv * gv0.z + bv0.z, (ss[3] - mu) * inv * gv0.w + bv0.w));
            ow.h2[2] = __float22half2_rn(make_float2(
                (ss[4] - mu) * inv * gv1.x + bv1.x, (ss[5] - mu) * inv * gv1.y + bv1.y));
            ow.h2[3] = __float22half2_rn(make_float2(
                (ss[6] - mu) * inv * gv1.z + bv1.z, (ss[7] - mu) * inv * gv1.w + bv1.w));
            *(uint4*)(Cbh + (size_t)node * HID_C + cbase) = ow.u;
        }
    }
}

// ================= pooling + projection =================
__device__ __forceinline__ int lower_bound_i(const int* __restrict__ a, int n, int v) {
    int lo = 0, hi = n;
    while (lo < hi) {
        int mid = (lo + hi) >> 1;
        if (a[mid] < v) lo = mid + 1; else hi = mid;
    }
    return lo;
}

__global__ void pool_kernel(const __half* __restrict__ H, const int* __restrict__ batch,
                            const float* __restrict__ q, float* __restrict__ pooled) {
    int g = blockIdx.x;
    int lane = threadIdx.x;
    int start = lower_bound_i(batch, N_NODES_C, g);
    int end = lower_bound_i(batch, N_NODES_C, g + 1);
    float q0 = q[lane * 2], q1 = q[lane * 2 + 1];
    float p0 = 0.f, p1 = 0.f, den = 0.f;
    for (int n = start; n < end; n++) {
        float2 hv = __half22float2(*(const __half2*)(H + (size_t)n * HID_C + lane * 2));
        float part = hv.x * q0 + hv.y * q1;
#pragma unroll
        for (int off = 1; off < 64; off <<= 1) part += __shfl_xor(part, off);
        float exs = __expf(part);
        den += exs;
        p0 = fmaf(exs, hv.x, p0);
        p1 = fmaf(exs, hv.y, p1);
    }
    float w = 1.f / (den + 1e-16f);
    pooled[(size_t)g * HID_C + lane * 2] = p0 * w;
    pooled[(size_t)g * HID_C + lane * 2 + 1] = p1 * w;
}

__global__ __launch_bounds__(128) void proj_kernel(const float* __restrict__ pooled,
                                                   const float* __restrict__ Wp,
                                                   const float* __restrict__ bp,
                                                   float* __restrict__ out) {
    int g = blockIdx.x, c = threadIdx.x;
    __shared__ float pl[HID_C];
    pl[c] = pooled[(size_t)g * HID_C + c];
    __syncthreads();
    float s = bp[c];
    for (int k = 0; k < HID_C; k++) s = fmaf(pl[k], Wp[k * HID_C + c], s);
    out[(size_t)g * HID_C + c] = s;
}

extern "C" void kernel_launch(void* const* d_in, const int* in_sizes, int n_in,
                              void* d_out, int out_size, void* d_ws, size_t ws_size,
                              hipStream_t stream) {
    const float* x   = (const float*)d_in[0];
    const int* ei    = (const int*)d_in[1];
    const int* batch = (const int*)d_in[2];
    const float* W1  = (const float*)d_in[3];
    const float* as1 = (const float*)d_in[4];
    const float* ad1 = (const float*)d_in[5];
    const float* b1  = (const float*)d_in[6];
    const float* W2  = (const float*)d_in[7];
    const float* as2 = (const float*)d_in[8];
    const float* ad2 = (const float*)d_in[9];
    const float* b2  = (const float*)d_in[10];
    const float* g1  = (const float*)d_in[11];
    const float* be1 = (const float*)d_in[12];
    const float* g2  = (const float*)d_in[13];
    const float* be2 = (const float*)d_in[14];
    const float* q   = (const float*)d_in[15];
    const float* Wp  = (const float*)d_in[16];
    const float* bp  = (const float*)d_in[17];
    float* out = (float*)d_out;

    const size_t NH = (size_t)N_NODES_C * HID_C;
    char* w = (char*)d_ws;
    __half* xh    = (__half*)w;   w += (size_t)N_NODES_C * IN_DIM_C * 2;
    __half* Cbh   = (__half*)w;   w += NH * 2;
    __half* Wt1   = (__half*)w;   w += (size_t)N_REL_C * IN_DIM_C * HID_C * 2;
    __half* Wt2   = (__half*)w;   w += (size_t)N_REL_C * HID_C * HID_C * 2;
    float* pooled = (float*)w;    w += (size_t)N_GRAPHS_C * HID_C * 4;
    int* rowptr   = (int*)w;      w += ((size_t)N_REL_C * (N_NODES_C + 1) * 4 + 15) & ~15ull;
    int* srcids   = (int*)w;      w += (size_t)N_REL_C * N_EDGES_C * 4;
    int* cnt      = (int*)w;      w += (size_t)N_REL_C * N_NODES_C * 4;
    int* cursor   = (int*)w;      w += (size_t)N_REL_C * N_NODES_C * 4;
    int* bsums    = (int*)w;      w += ((size_t)N_REL_C * NBLK_SCAN * 4 + 15) & ~15ull;

    const size_t fixed_bytes = (size_t)(w - (char*)d_ws);
    const size_t slot_bytes = NH * 2 + 2 * (size_t)N_NODES_C * HEADS_C * 4;
    int nA = 1;
    float* B = nullptr;
    {
        size_t rem = (ws_size > fixed_bytes) ? (ws_size - fixed_bytes) : 0;
        size_t k = rem / slot_bytes;
        if (k >= 6) {
            nA = 6;             // single group: no partial accumulator needed
        } else {
            size_t rem2 = (rem > NH * 4) ? (rem - NH * 4) : 0;
            size_t k2 = rem2 / slot_bytes;
            nA = (int)(k2 < 1 ? 1 : (k2 > 5 ? 5 : k2));
        }
    }
    float* als = (float*)w;
    float* ald = als + (size_t)nA * N_NODES_C * HEADS_C;
    __half* A  = (__half*)(ald + (size_t)nA * N_NODES_C * HEADS_C);
    if (nA < 6) B = (float*)(A + (size_t)nA * NH);

    // ---- CSR build ----
    hipMemsetAsync(cnt, 0, (size_t)N_REL_C * N_NODES_C * sizeof(int), stream);
    const int ehg = (N_REL_C * N_EDGES_C + 255) / 256;
    hist_kernel<<<ehg, 256, 0, stream>>>(ei, cnt);
    scan1_kernel<<<dim3(NBLK_SCAN, N_REL_C), 256, 0, stream>>>(cnt, rowptr, bsums);
    scan2_kernel<<<N_REL_C, 512, 0, stream>>>(bsums);
    scan3_kernel<<<dim3(NBLK_SCAN, N_REL_C), 256, 0, stream>>>(rowptr, bsums, cursor);
    scatter_kernel<<<ehg, 256, 0, stream>>>(ei, cursor, srcids);

    // ---- fp16 conversions ----
    convert_x_kernel<<<(N_NODES_C * IN_DIM_C / 4 + 255) / 256, 256, 0, stream>>>(
        x, xh, N_NODES_C * IN_DIM_C / 4);
    convert_w_kernel<<<(N_REL_C * HID_C * HID_C + 255) / 256, 256, 0, stream>>>(
        W1, W2, Wt1, Wt2);

    const int gemm_grid = (N_NODES_C + 63) / 64;
    const int agg_grid = N_NODES_C / 4;

    // ---- layer 1 ----
    for (int gs = 0; gs < N_REL_C; gs += nA) {
        int c2 = (N_REL_C - gs) < nA ? (N_REL_C - gs) : nA;
        gemm_mfma_kernel<IN_DIM_C><<<dim3(gemm_grid, c2), 256, 0, stream>>>(
            xh, Wt1 + (size_t)gs * IN_DIM_C * HID_C, A,
            as1 + gs * HID_C, ad1 + gs * HID_C, als, ald);
        csr_agg_kernel<<<agg_grid, 256, 0, stream>>>(
            rowptr, srcids, A, als, ald, gs, c2,
            b1, (gs == 0) ? 1 : 0, (gs + c2 == N_REL_C) ? 1 : 0,
            B, g1, be1, Cbh);
    }
    // ---- layer 2 ----
    for (int gs = 0; gs < N_REL_C; gs += nA) {
        int c2 = (N_REL_C - gs) < nA ? (N_REL_C - gs) : nA;
        gemm_mfma_kernel<HID_C><<<dim3(gemm_grid, c2), 256, 0, stream>>>(
            Cbh, Wt2 + (size_t)gs * HID_C * HID_C, A,
            as2 + gs * HID_C, ad2 + gs * HID_C, als, ald);
        csr_agg_kernel<<<agg_grid, 256, 0, stream>>>(
            rowptr, srcids, A, als, ald, gs, c2,
            b2, (gs == 0) ? 1 : 0, (gs + c2 == N_REL_C) ? 1 : 0,
            B, g2, be2, Cbh);
    }

    // ---- pooling + projection ----
    pool_kernel<<<N_GRAPHS_C, 64, 0, stream>>>(Cbh, batch, q, pooled);
    proj_kernel<<<N_GRAPHS_C, 128, 0, stream>>>(pooled, Wp, bp, out);
}

// Round 6
// 1112.660 us; speedup vs baseline: 1.9138x; 1.0961x over previous
//
#include <hip/hip_runtime.h>
#include <hip/hip_bf16.h>
#include <hip/hip_fp16.h>

#define N_NODES_C 100000
#define N_EDGES_C 500000
#define N_REL_C 6
#define IN_DIM_C 64
#define HID_C 128
#define HEADS_C 4
#define CPH_C 32
#define N_GRAPHS_C 1024
#define NBLK_SCAN 391   // ceil(100000/256)

typedef _Float16 f16x8 __attribute__((ext_vector_type(8)));
typedef float f32x4 __attribute__((ext_vector_type(4)));

// ================= CSR build =================
// hist + per-edge rank (atomicAdd return) in one pass
__global__ __launch_bounds__(256) void hist_rank_kernel(const int* __restrict__ ei,
                                                        int* __restrict__ cnt,
                                                        int* __restrict__ rank) {
    int i = blockIdx.x * 256 + threadIdx.x;
    if (i >= N_REL_C * N_EDGES_C) return;
    int r = i / N_EDGES_C;
    int e = i - r * N_EDGES_C;
    int dst = ei[(size_t)r * 2 * N_EDGES_C + N_EDGES_C + e];
    rank[i] = atomicAdd(&cnt[r * N_NODES_C + dst], 1);
}

__global__ __launch_bounds__(256) void scan1_kernel(const int* __restrict__ cnt,
                                                    int* __restrict__ rowptr,
                                                    int* __restrict__ blocksums) {
    int r = blockIdx.y, b = blockIdx.x, t = threadIdx.x;
    int idx = b * 256 + t;
    int v = (idx < N_NODES_C) ? cnt[r * N_NODES_C + idx] : 0;
    int orig = v;
    int lane = t & 63, w = t >> 6;
#pragma unroll
    for (int off = 1; off < 64; off <<= 1) {
        int n = __shfl_up(v, off);
        if (lane >= off) v += n;
    }
    __shared__ int wt[4];
    if (lane == 63) wt[w] = v;
    __syncthreads();
    int add = 0;
    for (int i = 0; i < w; i++) add += wt[i];
    v += add;
    if (idx < N_NODES_C) rowptr[(size_t)r * (N_NODES_C + 1) + idx] = v - orig;
    if (t == 255) blocksums[r * NBLK_SCAN + b] = v;
}

__global__ __launch_bounds__(512) void scan2_kernel(int* __restrict__ blocksums) {
    int r = blockIdx.x, t = threadIdx.x;
    int v = (t < NBLK_SCAN) ? blocksums[r * NBLK_SCAN + t] : 0;
    int orig = v;
    int lane = t & 63, w = t >> 6;
#pragma unroll
    for (int off = 1; off < 64; off <<= 1) {
        int n = __shfl_up(v, off);
        if (lane >= off) v += n;
    }
    __shared__ int wt[8];
    if (lane == 63) wt[w] = v;
    __syncthreads();
    int add = 0;
    for (int i = 0; i < w; i++) add += wt[i];
    v += add;
    if (t < NBLK_SCAN) blocksums[r * NBLK_SCAN + t] = v - orig;
}

__global__ __launch_bounds__(256) void scan3_kernel(int* __restrict__ rowptr,
                                                    const int* __restrict__ blocksums) {
    int r = blockIdx.y, b = blockIdx.x, t = threadIdx.x;
    int idx = b * 256 + t;
    if (idx < N_NODES_C) {
        rowptr[(size_t)r * (N_NODES_C + 1) + idx] += blocksums[r * NBLK_SCAN + b];
    }
    if (b == 0 && t == 0) rowptr[(size_t)r * (N_NODES_C + 1) + N_NODES_C] = N_EDGES_C;
}

// atomic-free scatter: pos = rowptr[dst] + rank[e]
__global__ __launch_bounds__(256) void scatter_kernel(const int* __restrict__ ei,
                                                      const int* __restrict__ rowptr,
                                                      const int* __restrict__ rank,
                                                      int* __restrict__ srcids) {
    int i = blockIdx.x * 256 + threadIdx.x;
    if (i >= N_REL_C * N_EDGES_C) return;
    int r = i / N_EDGES_C;
    int e = i - r * N_EDGES_C;
    int src = ei[(size_t)r * 2 * N_EDGES_C + e];
    int dst = ei[(size_t)r * 2 * N_EDGES_C + N_EDGES_C + e];
    int pos = rowptr[(size_t)r * (N_NODES_C + 1) + dst] + rank[i];
    srcids[(size_t)r * N_EDGES_C + pos] = src;
}

// ================= fp32 -> fp16 converts =================
__global__ __launch_bounds__(256) void convert_x_kernel(const float* __restrict__ x,
                                                        __half* __restrict__ xh, int n4) {
    int i = blockIdx.x * 256 + threadIdx.x;
    if (i >= n4) return;
    float4 v = ((const float4*)x)[i];
    union { __half h[4]; uint2 u; } u;
    u.h[0] = __float2half(v.x); u.h[1] = __float2half(v.y);
    u.h[2] = __float2half(v.z); u.h[3] = __float2half(v.w);
    ((uint2*)xh)[i] = u.u;
}

__global__ __launch_bounds__(256) void convert_w_kernel(const float* __restrict__ W1,
                                                        const float* __restrict__ W2,
                                                        __half* __restrict__ Wt1,
                                                        __half* __restrict__ Wt2) {
    int i = blockIdx.x * 256 + threadIdx.x;
    if (i < N_REL_C * IN_DIM_C * HID_C) {
        int r = i / (IN_DIM_C * HID_C);
        int rem = i - r * (IN_DIM_C * HID_C);
        int k = rem / HID_C, n = rem - k * HID_C;
        Wt1[(size_t)r * HID_C * IN_DIM_C + n * IN_DIM_C + k] = __float2half(W1[i]);
    }
    if (i < N_REL_C * HID_C * HID_C) {
        int r = i / (HID_C * HID_C);
        int rem = i - r * (HID_C * HID_C);
        int k = rem / HID_C, n = rem - k * HID_C;
        Wt2[(size_t)r * HID_C * HID_C + n * HID_C + k] = __float2half(W2[i]);
    }
}

// ================= fp16 MFMA GEMM + attn-logit epilogue =================
template <int K>
__global__ __launch_bounds__(256) void gemm_mfma_kernel(
    const __half* __restrict__ Xh, const __half* __restrict__ Wtbase,
    __half* __restrict__ Hbase,
    const float* __restrict__ asbase, const float* __restrict__ adbase,
    float* __restrict__ alsbase, float* __restrict__ aldbase) {
    const int slot = blockIdx.y;
    const __half* Wt = Wtbase + (size_t)slot * HID_C * K;
    __half* H = Hbase + (size_t)slot * N_NODES_C * HID_C;
    const int wave = threadIdx.x >> 6, lane = threadIdx.x & 63;
    const int r0 = blockIdx.x * 64 + wave * 16;
    const int m = lane & 15, quad = lane >> 4;
    int arow = r0 + m;
    if (arow > N_NODES_C - 1) arow = N_NODES_C - 1;
    const __half* ap = Xh + (size_t)arow * K + quad * 8;
    const __half* bp = Wt + (size_t)m * K + quad * 8;

    f32x4 acc[8];
#pragma unroll
    for (int t = 0; t < 8; t++) acc[t] = (f32x4){0.f, 0.f, 0.f, 0.f};

#pragma unroll
    for (int kc = 0; kc < K; kc += 32) {
        f16x8 a = *(const f16x8*)(ap + kc);
#pragma unroll
        for (int t = 0; t < 8; t++) {
            f16x8 b = *(const f16x8*)(bp + (size_t)t * 16 * K + kc);
            acc[t] = __builtin_amdgcn_mfma_f32_16x16x32_f16(a, b, acc[t], 0, 0, 0);
        }
    }

#pragma unroll
    for (int i = 0; i < 4; i++) {
        int R = r0 + quad * 4 + i;
        if (R < N_NODES_C) {
            __half* hp = H + (size_t)R * HID_C + m;
#pragma unroll
            for (int t = 0; t < 8; t++) hp[t * 16] = __float2half(acc[t][i]);
        }
    }

    const float* a_s = asbase + slot * HID_C;
    const float* a_d = adbase + slot * HID_C;
    float* als = alsbase + (size_t)slot * N_NODES_C * HEADS_C;
    float* ald = aldbase + (size_t)slot * N_NODES_C * HEADS_C;
    float ps[4][4], pd[4][4];
#pragma unroll
    for (int h = 0; h < 4; h++) {
        float as0 = a_s[h * 32 + m], as1 = a_s[h * 32 + 16 + m];
        float ad0 = a_d[h * 32 + m], ad1 = a_d[h * 32 + 16 + m];
#pragma unroll
        for (int i = 0; i < 4; i++) {
            ps[h][i] = acc[2 * h][i] * as0 + acc[2 * h + 1][i] * as1;
            pd[h][i] = acc[2 * h][i] * ad0 + acc[2 * h + 1][i] * ad1;
        }
    }
#pragma unroll
    for (int off = 1; off < 16; off <<= 1) {
#pragma unroll
        for (int h = 0; h < 4; h++)
#pragma unroll
            for (int i = 0; i < 4; i++) {
                ps[h][i] += __shfl_xor(ps[h][i], off);
                pd[h][i] += __shfl_xor(pd[h][i], off);
            }
    }
#pragma unroll
    for (int h = 0; h < 4; h++) {
        if (m == h) {
#pragma unroll
            for (int i = 0; i < 4; i++) {
                int R = r0 + quad * 4 + i;
                if (R < N_NODES_C) {
                    als[R * HEADS_C + h] = ps[h][i];
                    ald[R * HEADS_C + h] = pd[h][i];
                }
            }
        }
    }
}

// ========== fused multi-relation aggregate + bias + softsign + LN ==========
// one wave per dst node; 4 edge-groups of 16 lanes; lane j16 covers
// channels 8*j16..8*j16+7 (head = j16>>2). Groups stride the edge list by 4.
// Inner loop software-pipelined one edge ahead (row + logit prefetch).
__global__ __launch_bounds__(256) void csr_agg_kernel(
    const int* __restrict__ rowptr, const int* __restrict__ srcids,
    const __half* __restrict__ A, const float* __restrict__ als,
    const float* __restrict__ ald, int rel_start, int rel_cnt,
    const float* __restrict__ bias, int first, int last,
    float* __restrict__ B,
    const float* __restrict__ g, const float* __restrict__ be,
    __half* __restrict__ Cbh) {
    int node = blockIdx.x * 4 + (threadIdx.x >> 6);
    int lane = threadIdx.x & 63;
    int grp = lane >> 4;
    int j16 = lane & 15;
    int head = j16 >> 2;
    int cbase = j16 * 8;

    float acc[8];
    if (first) {
#pragma unroll
        for (int t = 0; t < 8; t++) {
            float s = 0.f;
#pragma unroll
            for (int r = 0; r < N_REL_C; r++) s += bias[r * HID_C + cbase + t];
            acc[t] = s;
        }
    } else {
        float4 b0 = *(const float4*)(B + (size_t)node * HID_C + cbase);
        float4 b1 = *(const float4*)(B + (size_t)node * HID_C + cbase + 4);
        acc[0] = b0.x; acc[1] = b0.y; acc[2] = b0.z; acc[3] = b0.w;
        acc[4] = b1.x; acc[5] = b1.y; acc[6] = b1.z; acc[7] = b1.w;
    }

    for (int j = 0; j < rel_cnt; j++) {
        int r = rel_start + j;
        const int* rp = rowptr + (size_t)r * (N_NODES_C + 1);
        const int* sp = srcids + (size_t)r * N_EDGES_C;
        const __half* Aj = A + (size_t)j * N_NODES_C * HID_C;
        const float* alj = als + (size_t)j * N_NODES_C * HEADS_C;
        float aldv = ald[(size_t)j * N_NODES_C * HEADS_C + node * HEADS_C + head];
        int s = rp[node], e = rp[node + 1];
        float racc[8];
#pragma unroll
        for (int t = 0; t < 8; t++) racc[t] = 0.f;
        float rden = 0.f;

        union HU { uint4 u; _Float16 h[8]; };
        int i = s + grp;
        int src = (i < e) ? sp[i] : 0;
        HU rw; rw.u = *(const uint4*)(Aj + (size_t)src * HID_C + cbase);
        float lg = alj[src * HEADS_C + head];
        for (; i < e; i += 4) {
            // prefetch next edge (clamped to src 0 — always valid memory)
            int nsrc = (i + 4 < e) ? sp[i + 4] : 0;
            HU nrw; nrw.u = *(const uint4*)(Aj + (size_t)nsrc * HID_C + cbase);
            float nlg = alj[nsrc * HEADS_C + head];
            float v = lg + aldv;
            v = fmaxf(v, 0.2f * v);          // leaky_relu
            float ex = __expf(v);
            rden += ex;
#pragma unroll
            for (int t = 0; t < 8; t++)
                racc[t] = fmaf((float)rw.h[t], ex, racc[t]);
            src = nsrc; rw = nrw; lg = nlg;
        }
#pragma unroll
        for (int off = 16; off < 64; off <<= 1) {
            rden += __shfl_xor(rden, off);
#pragma unroll
            for (int t = 0; t < 8; t++) racc[t] += __shfl_xor(racc[t], off);
        }
        float inv = 1.f / (rden + 1e-16f);
#pragma unroll
        for (int t = 0; t < 8; t++) acc[t] = fmaf(racc[t], inv, acc[t]);
    }

    if (!last) {
        if (grp == 0) {
            float4 o0 = make_float4(acc[0], acc[1], acc[2], acc[3]);
            float4 o1 = make_float4(acc[4], acc[5], acc[6], acc[7]);
            *(float4*)(B + (size_t)node * HID_C + cbase) = o0;
            *(float4*)(B + (size_t)node * HID_C + cbase + 4) = o1;
        }
    } else {
        float ss[8];
        float sum = 0.f, sq = 0.f;
#pragma unroll
        for (int t = 0; t < 8; t++) {
            float v = acc[t] / (1.f + fabsf(acc[t]));
            ss[t] = v;
            sum += v;
            sq = fmaf(v, v, sq);
        }
#pragma unroll
        for (int off = 1; off < 16; off <<= 1) {
            sum += __shfl_xor(sum, off);
            sq += __shfl_xor(sq, off);
        }
        float mu = sum * (1.f / 128.f);
        float var = sq * (1.f / 128.f) - mu * mu;
        float inv = rsqrtf(var + 1e-5f);
        if (grp == 0) {
            float4 gv0 = *(const float4*)(g + cbase);
            float4 gv1 = *(const float4*)(g + cbase + 4);
            float4 bv0 = *(const float4*)(be + cbase);
            float4 bv1 = *(const float4*)(be + cbase + 4);
            union { uint4 u; __half2 h2[4]; } ow;
            ow.h2[0] = __float22half2_rn(make_float2(
                (ss[0] - mu) * inv * gv0.x + bv0.x, (ss[1] - mu) * inv * gv0.y + bv0.y));
            ow.h2[1] = __float22half2_rn(make_float2(
                (ss[2] - mu) * inv * gv0.z + bv0.z, (ss[3] - mu) * inv * gv0.w + bv0.w));
            ow.h2[2] = __float22half2_rn(make_float2(
                (ss[4] - mu) * inv * gv1.x + bv1.x, (ss[5] - mu) * inv * gv1.y + bv1.y));
            ow.h2[3] = __float22half2_rn(make_float2(
                (ss[6] - mu) * inv * gv1.z + bv1.z, (ss[7] - mu) * inv * gv1.w + bv1.w));
            *(uint4*)(Cbh + (size_t)node * HID_C + cbase) = ow.u;
        }
    }
}

// ================= pooling + projection =================
__device__ __forceinline__ int lower_bound_i(const int* __restrict__ a, int n, int v) {
    int lo = 0, hi = n;
    while (lo < hi) {
        int mid = (lo + hi) >> 1;
        if (a[mid] < v) lo = mid + 1; else hi = mid;
    }
    return lo;
}

__global__ void pool_kernel(const __half* __restrict__ H, const int* __restrict__ batch,
                            const float* __restrict__ q, float* __restrict__ pooled) {
    int g = blockIdx.x;
    int lane = threadIdx.x;
    int start = lower_bound_i(batch, N_NODES_C, g);
    int end = lower_bound_i(batch, N_NODES_C, g + 1);
    float q0 = q[lane * 2], q1 = q[lane * 2 + 1];
    float p0 = 0.f, p1 = 0.f, den = 0.f;
    for (int n = start; n < end; n++) {
        float2 hv = __half22float2(*(const __half2*)(H + (size_t)n * HID_C + lane * 2));
        float part = hv.x * q0 + hv.y * q1;
#pragma unroll
        for (int off = 1; off < 64; off <<= 1) part += __shfl_xor(part, off);
        float exs = __expf(part);
        den += exs;
        p0 = fmaf(exs, hv.x, p0);
        p1 = fmaf(exs, hv.y, p1);
    }
    float w = 1.f / (den + 1e-16f);
    pooled[(size_t)g * HID_C + lane * 2] = p0 * w;
    pooled[(size_t)g * HID_C + lane * 2 + 1] = p1 * w;
}

__global__ __launch_bounds__(128) void proj_kernel(const float* __restrict__ pooled,
                                                   const float* __restrict__ Wp,
                                                   const float* __restrict__ bp,
                                                   float* __restrict__ out) {
    int g = blockIdx.x, c = threadIdx.x;
    __shared__ float pl[HID_C];
    pl[c] = pooled[(size_t)g * HID_C + c];
    __syncthreads();
    float s = bp[c];
    for (int k = 0; k < HID_C; k++) s = fmaf(pl[k], Wp[k * HID_C + c], s);
    out[(size_t)g * HID_C + c] = s;
}

extern "C" void kernel_launch(void* const* d_in, const int* in_sizes, int n_in,
                              void* d_out, int out_size, void* d_ws, size_t ws_size,
                              hipStream_t stream) {
    const float* x   = (const float*)d_in[0];
    const int* ei    = (const int*)d_in[1];
    const int* batch = (const int*)d_in[2];
    const float* W1  = (const float*)d_in[3];
    const float* as1 = (const float*)d_in[4];
    const float* ad1 = (const float*)d_in[5];
    const float* b1  = (const float*)d_in[6];
    const float* W2  = (const float*)d_in[7];
    const float* as2 = (const float*)d_in[8];
    const float* ad2 = (const float*)d_in[9];
    const float* b2  = (const float*)d_in[10];
    const float* g1  = (const float*)d_in[11];
    const float* be1 = (const float*)d_in[12];
    const float* g2  = (const float*)d_in[13];
    const float* be2 = (const float*)d_in[14];
    const float* q   = (const float*)d_in[15];
    const float* Wp  = (const float*)d_in[16];
    const float* bp  = (const float*)d_in[17];
    float* out = (float*)d_out;

    const size_t NH = (size_t)N_NODES_C * HID_C;
    char* w = (char*)d_ws;
    __half* xh    = (__half*)w;   w += (size_t)N_NODES_C * IN_DIM_C * 2;
    __half* Cbh   = (__half*)w;   w += NH * 2;
    __half* Wt1   = (__half*)w;   w += (size_t)N_REL_C * IN_DIM_C * HID_C * 2;
    __half* Wt2   = (__half*)w;   w += (size_t)N_REL_C * HID_C * HID_C * 2;
    float* pooled = (float*)w;    w += (size_t)N_GRAPHS_C * HID_C * 4;
    int* rowptr   = (int*)w;      w += ((size_t)N_REL_C * (N_NODES_C + 1) * 4 + 15) & ~15ull;
    int* srcids   = (int*)w;      w += (size_t)N_REL_C * N_EDGES_C * 4;
    int* cnt      = (int*)w;      w += (size_t)N_REL_C * N_NODES_C * 4;
    int* bsums    = (int*)w;      w += ((size_t)N_REL_C * NBLK_SCAN * 4 + 15) & ~15ull;

    const size_t fixed_bytes = (size_t)(w - (char*)d_ws);
    const size_t slot_bytes = NH * 2 + 2 * (size_t)N_NODES_C * HEADS_C * 4;
    int nA = 1;
    float* B = nullptr;
    {
        size_t rem = (ws_size > fixed_bytes) ? (ws_size - fixed_bytes) : 0;
        size_t k = rem / slot_bytes;
        if (k >= 6) {
            nA = 6;
        } else {
            size_t rem2 = (rem > NH * 4) ? (rem - NH * 4) : 0;
            size_t k2 = rem2 / slot_bytes;
            nA = (int)(k2 < 1 ? 1 : (k2 > 5 ? 5 : k2));
        }
    }
    float* als = (float*)w;
    float* ald = als + (size_t)nA * N_NODES_C * HEADS_C;
    __half* A  = (__half*)(ald + (size_t)nA * N_NODES_C * HEADS_C);
    if (nA < 6) B = (float*)(A + (size_t)nA * NH);
    // rank[] is only live during CSR build, before A is written: alias into A slab
    int* rank = (int*)A;   // 12 MB <= 25.6 MB (first slot)

    // ---- CSR build ----
    hipMemsetAsync(cnt, 0, (size_t)N_REL_C * N_NODES_C * sizeof(int), stream);
    const int ehg = (N_REL_C * N_EDGES_C + 255) / 256;
    hist_rank_kernel<<<ehg, 256, 0, stream>>>(ei, cnt, rank);
    scan1_kernel<<<dim3(NBLK_SCAN, N_REL_C), 256, 0, stream>>>(cnt, rowptr, bsums);
    scan2_kernel<<<N_REL_C, 512, 0, stream>>>(bsums);
    scan3_kernel<<<dim3(NBLK_SCAN, N_REL_C), 256, 0, stream>>>(rowptr, bsums);
    scatter_kernel<<<ehg, 256, 0, stream>>>(ei, rowptr, rank, srcids);

    // ---- fp16 conversions ----
    convert_x_kernel<<<(N_NODES_C * IN_DIM_C / 4 + 255) / 256, 256, 0, stream>>>(
        x, xh, N_NODES_C * IN_DIM_C / 4);
    convert_w_kernel<<<(N_REL_C * HID_C * HID_C + 255) / 256, 256, 0, stream>>>(
        W1, W2, Wt1, Wt2);

    const int gemm_grid = (N_NODES_C + 63) / 64;
    const int agg_grid = N_NODES_C / 4;

    // ---- layer 1 ----
    for (int gs = 0; gs < N_REL_C; gs += nA) {
        int c2 = (N_REL_C - gs) < nA ? (N_REL_C - gs) : nA;
        gemm_mfma_kernel<IN_DIM_C><<<dim3(gemm_grid, c2), 256, 0, stream>>>(
            xh, Wt1 + (size_t)gs * IN_DIM_C * HID_C, A,
            as1 + gs * HID_C, ad1 + gs * HID_C, als, ald);
        csr_agg_kernel<<<agg_grid, 256, 0, stream>>>(
            rowptr, srcids, A, als, ald, gs, c2,
            b1, (gs == 0) ? 1 : 0, (gs + c2 == N_REL_C) ? 1 : 0,
            B, g1, be1, Cbh);
    }
    // ---- layer 2 ----
    for (int gs = 0; gs < N_REL_C; gs += nA) {
        int c2 = (N_REL_C - gs) < nA ? (N_REL_C - gs) : nA;
        gemm_mfma_kernel<HID_C><<<dim3(gemm_grid, c2), 256, 0, stream>>>(
            Cbh, Wt2 + (size_t)gs * HID_C * HID_C, A,
            as2 + gs * HID_C, ad2 + gs * HID_C, als, ald);
        csr_agg_kernel<<<agg_grid, 256, 0, stream>>>(
            rowptr, srcids, A, als, ald, gs, c2,
            b2, (gs == 0) ? 1 : 0, (gs + c2 == N_REL_C) ? 1 : 0,
            B, g2, be2, Cbh);
    }

    // ---- pooling + projection ----
    pool_kernel<<<N_GRAPHS_C, 64, 0, stream>>>(Cbh, batch, q, pooled);
    proj_kernel<<<N_GRAPHS_C, 128, 0, stream>>>(pooled, Wp, bp, out);
}